// Round 5
// baseline (876.746 us; speedup 1.0000x reference)
//
#include <hip/hip_runtime.h>
#include <hip/hip_bf16.h>

#define NN 100000
#define NE 800000
#define SCAN_NB 98   // ceil(NN / 1024)

typedef __attribute__((ext_vector_type(8))) short bf16x8;
typedef __attribute__((ext_vector_type(4))) float f32x4;

__device__ __forceinline__ short f2b(float f) {
    unsigned u = __float_as_uint(f);
    unsigned r = (u + 0x7fffu + ((u >> 16) & 1u)) >> 16;
    return (short)r;
}
__device__ __forceinline__ float b2f(short s) {
    return __uint_as_float(((unsigned)(unsigned short)s) << 16);
}

// ---------------- CSR build ----------------
__global__ __launch_bounds__(256) void k_hist(const int* __restrict__ ei, int* __restrict__ deg)
{
    int e = blockIdx.x * 256 + threadIdx.x;
    if (e < NE) atomicAdd(&deg[ei[NE + e]], 1);
}

__global__ __launch_bounds__(1024) void k_scan_a(const int* __restrict__ deg,
    int* __restrict__ tmp, int* __restrict__ bsum)
{
    __shared__ int sh[1024];
    int t = threadIdx.x, b = blockIdx.x;
    int idx = b * 1024 + t;
    int v = (idx < NN) ? deg[idx] : 0;
    sh[t] = v;
    __syncthreads();
    for (int ofs = 1; ofs < 1024; ofs <<= 1) {
        int u = (t >= ofs) ? sh[t - ofs] : 0;
        __syncthreads();
        sh[t] += u;
        __syncthreads();
    }
    if (idx < NN) tmp[idx] = sh[t] - v;
    if (t == 1023) bsum[b] = sh[1023];
}

__global__ void k_scan_b(const int* __restrict__ bsum, int* __restrict__ boff,
    int* __restrict__ rowptr)
{
    if (threadIdx.x == 0) {
        int acc = 0;
        for (int i = 0; i < SCAN_NB; i++) { boff[i] = acc; acc += bsum[i]; }
        rowptr[NN] = acc;
    }
}

__global__ __launch_bounds__(1024) void k_scan_c(const int* __restrict__ tmp,
    const int* __restrict__ boff, int* __restrict__ rowptr, int* __restrict__ wp)
{
    int b = blockIdx.x, t = threadIdx.x;
    int idx = b * 1024 + t;
    if (idx < NN) {
        int v = boff[b] + tmp[idx];
        rowptr[idx] = v; wp[idx] = v;
    }
}

__global__ __launch_bounds__(256) void k_scatter(const int* __restrict__ ei,
    int* __restrict__ wp, int* __restrict__ elist)
{
    int e = blockIdx.x * 256 + threadIdx.x;
    if (e < NE) {
        int d = ei[NE + e];
        int pos = atomicAdd(&wp[d], 1);
        elist[pos] = ei[e];
    }
}

// ---------------- gather aggregation ----------------
__global__ __launch_bounds__(256) void k_gagg1(const float* __restrict__ x,
    const int* __restrict__ rowptr, const int* __restrict__ elist, float* __restrict__ meanX)
{
    int n = blockIdx.x * 8 + (threadIdx.x >> 5);
    int j = threadIdx.x & 31;
    int b = rowptr[n], e = rowptr[n + 1];
    float acc = 0.f;
    for (int i = b; i < e; i++) {
        int s = elist[i];
        acc += x[(size_t)s * 32 + j];
    }
    float inv = (e > b) ? 1.0f / (float)(e - b) : 1.0f;
    meanX[(size_t)n * 32 + j] = acc * inv;
}

// 8 nodes/block, 32 lanes/node, ushort4/lane; bn1 fin computed in-block
__global__ __launch_bounds__(256) void k_gagg2(const short* __restrict__ h1b,
    const int* __restrict__ rowptr, const int* __restrict__ elist,
    const float* __restrict__ ssum, const float* __restrict__ ssq,
    const float* __restrict__ g, const float* __restrict__ bb, short* __restrict__ m2b)
{
    __shared__ float sS[128], sH[128];
    int tid = threadIdx.x;
    if (tid < 128) {
        float m = ssum[tid] / (float)NN;
        float var = ssq[tid] / (float)NN - m * m;
        float rs = rsqrtf(var + 1e-5f);
        float sc = g[tid] * rs;
        sS[tid] = sc; sH[tid] = bb[tid] - m * sc;
    }
    __syncthreads();
    int n = blockIdx.x * 8 + (tid >> 5);
    int c0 = (tid & 31) * 4;
    float sc[4], sh[4];
    #pragma unroll
    for (int i = 0; i < 4; i++) { sc[i] = sS[c0 + i]; sh[i] = sH[c0 + i]; }
    int b = rowptr[n], e = rowptr[n + 1];
    float acc[4] = {0.f, 0.f, 0.f, 0.f};
    for (int i = b; i < e; i++) {
        int s = elist[i];
        ushort4 u = *(const ushort4*)(h1b + (size_t)s * 128 + c0);
        acc[0] += fmaxf(b2f((short)u.x) * sc[0] + sh[0], 0.f);
        acc[1] += fmaxf(b2f((short)u.y) * sc[1] + sh[1], 0.f);
        acc[2] += fmaxf(b2f((short)u.z) * sc[2] + sh[2], 0.f);
        acc[3] += fmaxf(b2f((short)u.w) * sc[3] + sh[3], 0.f);
    }
    float inv = (e > b) ? 1.0f / (float)(e - b) : 1.0f;
    ushort4 o;
    o.x = (unsigned short)f2b(acc[0] * inv);
    o.y = (unsigned short)f2b(acc[1] * inv);
    o.z = (unsigned short)f2b(acc[2] * inv);
    o.w = (unsigned short)f2b(acc[3] * inv);
    *(ushort4*)(m2b + (size_t)n * 128 + c0) = o;
}

// ---------------- SAGE layer 1 (fp32 VALU), writes h1b bf16 + stats ----------------
__global__ __launch_bounds__(256) void k_node_l1(
    const float* __restrict__ meanX, const float* __restrict__ x,
    const float* __restrict__ Wl, const float* __restrict__ Wr,
    const float* __restrict__ bias,
    short* __restrict__ outp, float* __restrict__ ssum, float* __restrict__ ssq)
{
    __shared__ __align__(16) float sWl[32][128];
    __shared__ __align__(16) float sWr[32][128];
    __shared__ __align__(16) float sA[32][36];
    __shared__ __align__(16) float sB[32][36];
    __shared__ float red[2][128], red2[2][128];
    int tid = threadIdx.x;
    int j = tid & 127, rg = tid >> 7;
    int r0 = blockIdx.x * 32;

    for (int f = tid * 4; f < 4096; f += 1024) {
        *(float4*)((float*)sWl + f) = *(const float4*)(Wl + f);
        *(float4*)((float*)sWr + f) = *(const float4*)(Wr + f);
    }
    {
        int r = tid >> 3, c = (tid & 7) * 4;
        *(float4*)(&sA[r][c]) = *(const float4*)(meanX + (size_t)(r0 + r) * 32 + c);
        *(float4*)(&sB[r][c]) = *(const float4*)(x + (size_t)(r0 + r) * 32 + c);
    }
    __syncthreads();

    float acc[16];
    #pragma unroll
    for (int r = 0; r < 16; r++) acc[r] = 0.0f;
    int rb = rg * 16;
    #pragma unroll
    for (int kq = 0; kq < 8; kq++) {
        int k = kq * 4;
        float wl0 = sWl[k][j], wl1 = sWl[k+1][j], wl2 = sWl[k+2][j], wl3 = sWl[k+3][j];
        float wr0 = sWr[k][j], wr1 = sWr[k+1][j], wr2 = sWr[k+2][j], wr3 = sWr[k+3][j];
        #pragma unroll
        for (int r = 0; r < 16; r++) {
            float4 a = *(float4*)(&sA[rb + r][k]);
            float4 b = *(float4*)(&sB[rb + r][k]);
            acc[r] += a.x*wl0 + a.y*wl1 + a.z*wl2 + a.w*wl3
                    + b.x*wr0 + b.y*wr1 + b.z*wr2 + b.w*wr3;
        }
    }
    float bj = bias[j];
    float s1 = 0.0f, s2 = 0.0f;
    #pragma unroll
    for (int r = 0; r < 16; r++) {
        float v = acc[r] + bj;
        outp[(size_t)(r0 + rb + r) * 128 + j] = f2b(v);
        s1 += v; s2 += v * v;
    }
    red[rg][j] = s1; red2[rg][j] = s2;
    __syncthreads();
    if (rg == 0) {
        atomicAdd(&ssum[j], red[0][j] + red[1][j]);
        atomicAdd(&ssq[j],  red2[0][j] + red2[1][j]);
    }
}

// ---------------- SAGE layer 2 via MFMA (bn1 fin in-block) ----------------
__global__ __launch_bounds__(256) void k_node_l2m(
    const short* __restrict__ m2b, const short* __restrict__ h1b,
    const float* __restrict__ s1sum, const float* __restrict__ s1sq,
    const float* __restrict__ g1, const float* __restrict__ b1b,
    const short* __restrict__ W2cT, const float* __restrict__ bias,
    short* __restrict__ h2b, float* __restrict__ ssum, float* __restrict__ ssq)
{
    __shared__ __align__(16) short sK[32][264];
    __shared__ float sRed[2][128];
    __shared__ float sS[128], sH[128];
    const int tid = threadIdx.x;
    const int wave = tid >> 6, lane = tid & 63, quad = lane >> 4, ln = lane & 15;
    const int waveM = wave >> 1, waveN = wave & 1;
    const int colbase = 64 * waveN, row16 = 16 * waveM;
    if (tid < 128) {
        float m = s1sum[tid] / (float)NN;
        float var = s1sq[tid] / (float)NN - m * m;
        float rs = rsqrtf(var + 1e-5f);
        float sc = g1[tid] * rs;
        sS[tid] = sc; sH[tid] = b1b[tid] - m * sc;
        sRed[0][tid] = 0.f; sRed[1][tid] = 0.f;
    }

    bf16x8 bW[4][8];
    #pragma unroll
    for (int nt = 0; nt < 4; nt++)
        #pragma unroll
        for (int kk = 0; kk < 8; kk++)
            bW[nt][kk] = *(const bf16x8*)(W2cT + (size_t)(colbase + nt * 16 + ln) * 256 + kk * 32 + quad * 8);
    float bc[4];
    #pragma unroll
    for (int nt = 0; nt < 4; nt++) bc[nt] = bias[colbase + nt * 16 + ln];

    float s1[4] = {0,0,0,0}, s2[4] = {0,0,0,0};
    f32x4 zero = {0.f, 0.f, 0.f, 0.f};
    __syncthreads();

    for (int t = blockIdx.x; t < NN / 32; t += gridDim.x) {
        int r0 = t * 32;
        __syncthreads();
        {
            int r = tid >> 3, seg = tid & 7;
            if (seg < 4) {
                const bf16x8* src = (const bf16x8*)(m2b + (size_t)(r0 + r) * 128 + seg * 32);
                bf16x8* dst = (bf16x8*)(&sK[r][seg * 32]);
                dst[0] = src[0]; dst[1] = src[1]; dst[2] = src[2]; dst[3] = src[3];
            } else {
                int c0 = (seg - 4) * 32;
                const short* src = h1b + (size_t)(r0 + r) * 128 + c0;
                short tmp[32];
                #pragma unroll
                for (int i = 0; i < 32; i++)
                    tmp[i] = f2b(fmaxf(b2f(src[i]) * sS[c0 + i] + sH[c0 + i], 0.f));
                bf16x8* dst = (bf16x8*)(&sK[r][128 + c0]);
                dst[0] = *(bf16x8*)(tmp); dst[1] = *(bf16x8*)(tmp + 8);
                dst[2] = *(bf16x8*)(tmp + 16); dst[3] = *(bf16x8*)(tmp + 24);
            }
        }
        __syncthreads();
        f32x4 acc[4] = {zero, zero, zero, zero};
        #pragma unroll
        for (int kk = 0; kk < 8; kk++) {
            bf16x8 a = *(const bf16x8*)(&sK[row16 + ln][kk * 32 + quad * 8]);
            #pragma unroll
            for (int nt = 0; nt < 4; nt++)
                acc[nt] = __builtin_amdgcn_mfma_f32_16x16x32_bf16(a, bW[nt][kk], acc[nt], 0, 0, 0);
        }
        #pragma unroll
        for (int nt = 0; nt < 4; nt++) {
            int col = colbase + nt * 16 + ln;
            #pragma unroll
            for (int r = 0; r < 4; r++) {
                float v = acc[nt][r] + bc[nt];
                h2b[(size_t)(r0 + row16 + quad * 4 + r) * 128 + col] = f2b(v);
                s1[nt] += v; s2[nt] += v * v;
            }
        }
    }
    #pragma unroll
    for (int nt = 0; nt < 4; nt++) {
        float a1 = s1[nt], a2 = s2[nt];
        a1 += __shfl_down(a1, 32); a1 += __shfl_down(a1, 16);
        a2 += __shfl_down(a2, 32); a2 += __shfl_down(a2, 16);
        if (quad == 0) {
            atomicAdd(&sRed[0][colbase + nt * 16 + ln], a1);
            atomicAdd(&sRed[1][colbase + nt * 16 + ln], a2);
        }
    }
    __syncthreads();
    if (tid < 128) {
        atomicAdd(&ssum[tid], sRed[0][tid]);
        atomicAdd(&ssq[tid],  sRed[1][tid]);
    }
}

// ---------------- prep: transposed bf16 weights ----------------
__global__ void k_prep(const float* __restrict__ We, const float* __restrict__ Wm1,
                       const float* __restrict__ W2l, const float* __restrict__ W2r,
                       short* __restrict__ WteT, short* __restrict__ WmsT,
                       short* __restrict__ WmdT, short* __restrict__ W2cT)
{
    int j = threadIdx.x;  // 128
    int b = blockIdx.x;
    if (b == 0) {
        for (int k = 0; k < 32; k++)
            WteT[j * 32 + k] = (k < 16) ? f2b(We[k * 128 + j]) : (short)0;
    } else if (b == 1) {
        for (int k = 0; k < 128; k++) WmsT[j * 128 + k] = f2b(Wm1[k * 128 + j]);
    } else if (b == 2) {
        for (int k = 0; k < 128; k++) WmdT[j * 128 + k] = f2b(Wm1[(128 + k) * 128 + j]);
    } else if (b == 3) {
        for (int k = 0; k < 128; k++) W2cT[j * 256 + k] = f2b(W2l[k * 128 + j]);
    } else {
        for (int k = 0; k < 128; k++) W2cT[j * 256 + 128 + k] = f2b(W2r[k * 128 + j]);
    }
}

// ---------------- fold bne into Wm1[256:384] -> W1pT ----------------
__global__ void k_fold_e(const float* __restrict__ ssum, const float* __restrict__ ssq,
    const float* __restrict__ g, const float* __restrict__ b,
    const float* __restrict__ Wm1, const float* __restrict__ bm1,
    short* __restrict__ W1pT, float* __restrict__ bm1p)
{
    __shared__ float sa[128], sc[128];
    int tid = threadIdx.x;
    float m = ssum[tid] / (float)NE;
    float var = ssq[tid] / (float)NE - m * m;
    float rs = rsqrtf(var + 1e-5f);
    float a = g[tid] * rs;
    sa[tid] = a; sc[tid] = b[tid] - m * a;
    __syncthreads();
    float acc = bm1[tid];
    for (int k = 0; k < 128; k++) {
        float w = Wm1[(256 + k) * 128 + tid];
        W1pT[tid * 128 + k] = f2b(sa[k] * w);
        acc += sc[k] * w;
    }
    bm1p[tid] = acc;
}

// ---------------- fold bnm into Wm2 -> W2pT ----------------
__global__ void k_fold_m(const float* __restrict__ ssum, const float* __restrict__ ssq,
    const float* __restrict__ g, const float* __restrict__ b,
    const float* __restrict__ Wm2, const float* __restrict__ bm2,
    short* __restrict__ W2pT, float* __restrict__ b2p)
{
    __shared__ float sa[128], sc[128];
    int tid = threadIdx.x;
    float m = ssum[tid] / (float)NE;
    float var = ssq[tid] / (float)NE - m * m;
    float rs = rsqrtf(var + 1e-5f);
    float a = g[tid] * rs;
    sa[tid] = a; sc[tid] = b[tid] - m * a;
    __syncthreads();
    if (tid < 64) {
        float acc = bm2[tid];
        for (int k = 0; k < 128; k++) {
            float w = Wm2[k * 64 + tid];
            W2pT[tid * 128 + k] = f2b(sa[k] * w);
            acc += sc[k] * w;
        }
        b2p[tid] = acc;
    }
}

// ---------------- merged node projections: hs/hd = bnrelu(h2b) @ {Wms,Wmd} ----------------
__global__ __launch_bounds__(256) void k_proj2(
    const short* __restrict__ h2b,
    const float* __restrict__ s2sum, const float* __restrict__ s2sq,
    const float* __restrict__ g2, const float* __restrict__ b2b,
    const short* __restrict__ WsT, const short* __restrict__ WdT,
    short* __restrict__ Cs, short* __restrict__ Cd)
{
    __shared__ __align__(16) short sA[32][136];
    __shared__ float sS[128], sH[128];
    const int tid = threadIdx.x;
    const int wave = tid >> 6, lane = tid & 63, quad = lane >> 4, ln = lane & 15;
    const int waveM = wave >> 1, waveN = wave & 1;
    const int colbase = 64 * waveN, row16 = 16 * waveM;
    if (tid < 128) {
        float m = s2sum[tid] / (float)NN;
        float var = s2sq[tid] / (float)NN - m * m;
        float rs = rsqrtf(var + 1e-5f);
        float sc = g2[tid] * rs;
        sS[tid] = sc; sH[tid] = b2b[tid] - m * sc;
    }
    bf16x8 bWs[4][4], bWd[4][4];
    #pragma unroll
    for (int nt = 0; nt < 4; nt++)
        #pragma unroll
        for (int kk = 0; kk < 4; kk++) {
            bWs[nt][kk] = *(const bf16x8*)(WsT + (colbase + nt * 16 + ln) * 128 + kk * 32 + quad * 8);
            bWd[nt][kk] = *(const bf16x8*)(WdT + (colbase + nt * 16 + ln) * 128 + kk * 32 + quad * 8);
        }
    f32x4 zero = {0.f, 0.f, 0.f, 0.f};
    __syncthreads();
    for (int t = blockIdx.x; t < NN / 32; t += gridDim.x) {
        int r0 = t * 32;
        __syncthreads();
        {
            int r = tid >> 3, c0 = (tid & 7) * 16;
            const short* p = h2b + (size_t)(r0 + r) * 128 + c0;
            short tmp[16];
            #pragma unroll
            for (int i = 0; i < 16; i++)
                tmp[i] = f2b(fmaxf(b2f(p[i]) * sS[c0 + i] + sH[c0 + i], 0.f));
            *(bf16x8*)(&sA[r][c0])     = *(bf16x8*)tmp;
            *(bf16x8*)(&sA[r][c0 + 8]) = *(bf16x8*)(tmp + 8);
        }
        __syncthreads();
        f32x4 accS[4] = {zero, zero, zero, zero};
        f32x4 accD[4] = {zero, zero, zero, zero};
        #pragma unroll
        for (int kk = 0; kk < 4; kk++) {
            bf16x8 a = *(const bf16x8*)(&sA[row16 + ln][kk * 32 + quad * 8]);
            #pragma unroll
            for (int nt = 0; nt < 4; nt++) {
                accS[nt] = __builtin_amdgcn_mfma_f32_16x16x32_bf16(a, bWs[nt][kk], accS[nt], 0, 0, 0);
                accD[nt] = __builtin_amdgcn_mfma_f32_16x16x32_bf16(a, bWd[nt][kk], accD[nt], 0, 0, 0);
            }
        }
        #pragma unroll
        for (int nt = 0; nt < 4; nt++) {
            int col = colbase + nt * 16 + ln;
            #pragma unroll
            for (int r = 0; r < 4; r++) {
                size_t idx = (size_t)(r0 + row16 + quad * 4 + r) * 128 + col;
                Cs[idx] = f2b(accS[nt][r]);
                Cd[idx] = f2b(accD[nt][r]);
            }
        }
    }
}

// ---------------- edge pipeline via MFMA ----------------
// MODE 0: bne stats of t = relu(ea@We+be); writes ea_bf (bf16 copy of ea)
// MODE 1: v = relu(t@W1p + bm1p + hs[es] + hd[et]); bnm stats  (LDS-staged gathers)
// MODE 2: recompute v; z2 = relu(v@W2p + b2p); out = z2@Wm3 + bm3
template<int MODE>
__global__ __launch_bounds__(256) void k_edge_mfma(
    const float* __restrict__ ea, short* __restrict__ ea_bf,
    const short* __restrict__ WteT, const float* __restrict__ be,
    const short* __restrict__ W1pT, const float* __restrict__ bm1p,
    const short* __restrict__ hs, const short* __restrict__ hd,
    const int* __restrict__ esrc, const int* __restrict__ etgt,
    const short* __restrict__ W2pT, const float* __restrict__ b2p,
    const float* __restrict__ Wm3, const float* __restrict__ bm3,
    float* __restrict__ ssum, float* __restrict__ ssq,
    float* __restrict__ outp)
{
    __shared__ __align__(16) short sT[32][136];
    __shared__ float sRed[2][128];
    __shared__ __align__(16) float sG[32][132];   // hs[es]+hd[et] staged
    __shared__ __align__(16) short sW2[64][136];
    __shared__ float sZ[32][69];
    __shared__ float sW3[64];

    const int tid = threadIdx.x;
    const int wave = tid >> 6, lane = tid & 63;
    const int quad = lane >> 4, ln = lane & 15;
    const int waveM = wave >> 1, waveN = wave & 1;
    const int colbase = 64 * waveN, row16 = 16 * waveM;

    if (MODE < 2) {
        if (tid < 128) { sRed[0][tid] = 0.f; sRed[1][tid] = 0.f; }
    }
    if (MODE == 2) {
        int q = tid >> 2, kb = (tid & 3) * 32;
        const bf16x8* src = (const bf16x8*)(W2pT + q * 128 + kb);
        bf16x8* dst = (bf16x8*)(&sW2[q][kb]);
        dst[0] = src[0]; dst[1] = src[1]; dst[2] = src[2]; dst[3] = src[3];
        if (tid < 64) sW3[tid] = Wm3[tid];
    }

    bf16x8 bWe[4], bW1[4][4];
    #pragma unroll
    for (int nt = 0; nt < 4; nt++) {
        bWe[nt] = *(const bf16x8*)(WteT + (colbase + nt * 16 + ln) * 32 + quad * 8);
        if (MODE >= 1) {
            #pragma unroll
            for (int kk = 0; kk < 4; kk++)
                bW1[nt][kk] = *(const bf16x8*)(W1pT + (colbase + nt * 16 + ln) * 128 + kk * 32 + quad * 8);
        }
    }
    float bec[4], bmc[4];
    #pragma unroll
    for (int nt = 0; nt < 4; nt++) {
        bec[nt] = be[colbase + nt * 16 + ln];
        bmc[nt] = (MODE >= 1) ? bm1p[colbase + nt * 16 + ln] : 0.f;
    }
    float b2c[2] = {0.f, 0.f};
    if (MODE == 2) { b2c[0] = b2p[32 * waveN + ln]; b2c[1] = b2p[32 * waveN + 16 + ln]; }
    float bm3v = (MODE == 2) ? bm3[0] : 0.f;

    const int g_er = tid >> 3, g_cb = (tid & 7) * 16;   // gather mapping

    float s1[4] = {0,0,0,0}, s2[4] = {0,0,0,0};
    f32x4 zero = {0.f, 0.f, 0.f, 0.f};
    __syncthreads();

    for (int t = blockIdx.x; t < NE / 32; t += gridDim.x) {
        const int e0 = t * 32;

        // ---- issue gather loads early (registers, no LDS dep) ----
        bf16x8 ga0, ga1, gb0, gb1;
        if (MODE >= 1) {
            int es_ = esrc[e0 + g_er], et_ = etgt[e0 + g_er];
            const short* ps = hs + (size_t)es_ * 128 + g_cb;
            const short* pd = hd + (size_t)et_ * 128 + g_cb;
            ga0 = *(const bf16x8*)ps;      ga1 = *(const bf16x8*)(ps + 8);
            gb0 = *(const bf16x8*)pd;      gb1 = *(const bf16x8*)(pd + 8);
        }

        // ---- t-GEMM input ----
        bf16x8 aE;
        #pragma unroll
        for (int i = 0; i < 8; i++) aE[i] = 0;
        if (MODE == 0) {
            if (quad < 2) {
                const float* p = ea + (size_t)(e0 + row16 + ln) * 16 + quad * 8;
                float4 f0 = *(const float4*)p, f1 = *(const float4*)(p + 4);
                aE[0]=f2b(f0.x); aE[1]=f2b(f0.y); aE[2]=f2b(f0.z); aE[3]=f2b(f0.w);
                aE[4]=f2b(f1.x); aE[5]=f2b(f1.y); aE[6]=f2b(f1.z); aE[7]=f2b(f1.w);
                if (waveN == 0)
                    *(bf16x8*)(ea_bf + (size_t)(e0 + row16 + ln) * 16 + quad * 8) = aE;
            }
        } else {
            if (quad < 2)
                aE = *(const bf16x8*)(ea_bf + (size_t)(e0 + row16 + ln) * 16 + quad * 8);
        }
        f32x4 tacc[4];
        #pragma unroll
        for (int nt = 0; nt < 4; nt++)
            tacc[nt] = __builtin_amdgcn_mfma_f32_16x16x32_bf16(aE, bWe[nt], tacc[nt] = zero, 0, 0, 0);

        if (MODE == 0) {
            #pragma unroll
            for (int nt = 0; nt < 4; nt++)
                #pragma unroll
                for (int r = 0; r < 4; r++) {
                    float v = fmaxf(tacc[nt][r] + bec[nt], 0.f);
                    s1[nt] += v; s2[nt] += v * v;
                }
            continue;
        }

        __syncthreads();   // prev-iter sT/sG reads done
        #pragma unroll
        for (int nt = 0; nt < 4; nt++) {
            int col = colbase + nt * 16 + ln;
            #pragma unroll
            for (int r = 0; r < 4; r++)
                sT[row16 + quad * 4 + r][col] = f2b(fmaxf(tacc[nt][r] + bec[nt], 0.f));
        }
        {
            float tf[16];
            #pragma unroll
            for (int i = 0; i < 8; i++) {
                tf[i]     = b2f(ga0[i]) + b2f(gb0[i]);
                tf[8 + i] = b2f(ga1[i]) + b2f(gb1[i]);
            }
            #pragma unroll
            for (int q4 = 0; q4 < 4; q4++)
                *(float4*)(&sG[g_er][g_cb + q4 * 4]) = *(float4*)(tf + q4 * 4);
        }
        __syncthreads();

        // ---- u-GEMM ----
        f32x4 uacc[4] = {zero, zero, zero, zero};
        #pragma unroll
        for (int kk = 0; kk < 4; kk++) {
            bf16x8 aU = *(const bf16x8*)(&sT[row16 + ln][kk * 32 + quad * 8]);
            #pragma unroll
            for (int nt = 0; nt < 4; nt++)
                uacc[nt] = __builtin_amdgcn_mfma_f32_16x16x32_bf16(aU, bW1[nt][kk], uacc[nt], 0, 0, 0);
        }

        if (MODE == 1) {
            #pragma unroll
            for (int nt = 0; nt < 4; nt++) {
                int col = colbase + nt * 16 + ln;
                #pragma unroll
                for (int r = 0; r < 4; r++) {
                    float v = uacc[nt][r] + bmc[nt] + sG[row16 + quad * 4 + r][col];
                    v = fmaxf(v, 0.f);
                    s1[nt] += v; s2[nt] += v * v;
                }
            }
        } else {
            __syncthreads();   // u-GEMM sT reads done
            #pragma unroll
            for (int nt = 0; nt < 4; nt++) {
                int col = colbase + nt * 16 + ln;
                #pragma unroll
                for (int r = 0; r < 4; r++) {
                    float v = uacc[nt][r] + bmc[nt] + sG[row16 + quad * 4 + r][col];
                    sT[row16 + quad * 4 + r][col] = f2b(fmaxf(v, 0.f));
                }
            }
            __syncthreads();
            f32x4 vacc[2] = {zero, zero};
            #pragma unroll
            for (int kk = 0; kk < 4; kk++) {
                bf16x8 aV = *(const bf16x8*)(&sT[row16 + ln][kk * 32 + quad * 8]);
                #pragma unroll
                for (int n2 = 0; n2 < 2; n2++) {
                    bf16x8 bV = *(const bf16x8*)(&sW2[32 * waveN + n2 * 16 + ln][kk * 32 + quad * 8]);
                    vacc[n2] = __builtin_amdgcn_mfma_f32_16x16x32_bf16(aV, bV, vacc[n2], 0, 0, 0);
                }
            }
            #pragma unroll
            for (int n2 = 0; n2 < 2; n2++) {
                int col2 = 32 * waveN + n2 * 16 + ln;
                #pragma unroll
                for (int r = 0; r < 4; r++)
                    sZ[row16 + quad * 4 + r][col2] = fmaxf(vacc[n2][r] + b2c[n2], 0.f);
            }
            __syncthreads();
            if (wave == 0) {
                int rw = lane & 31, half = lane >> 5;
                float o = 0.f;
                #pragma unroll 8
                for (int k2 = 0; k2 < 32; k2++)
                    o += sZ[rw][half * 32 + k2] * sW3[half * 32 + k2];
                o += __shfl_down(o, 32);
                if (lane < 32) outp[e0 + rw] = o + bm3v;
            }
        }
    }

    if (MODE < 2) {
        #pragma unroll
        for (int nt = 0; nt < 4; nt++) {
            float a1 = s1[nt], a2 = s2[nt];
            a1 += __shfl_down(a1, 32); a1 += __shfl_down(a1, 16);
            a2 += __shfl_down(a2, 32); a2 += __shfl_down(a2, 16);
            if (quad == 0) {
                atomicAdd(&sRed[0][colbase + nt * 16 + ln], a1);
                atomicAdd(&sRed[1][colbase + nt * 16 + ln], a2);
            }
        }
        __syncthreads();
        if (tid < 128) {
            atomicAdd(&ssum[tid], sRed[0][tid]);
            atomicAdd(&ssq[tid],  sRed[1][tid]);
        }
    }
}

extern "C" void kernel_launch(void* const* d_in, const int* in_sizes, int n_in,
                              void* d_out, int out_size, void* d_ws, size_t ws_size,
                              hipStream_t stream) {
    const float* x     = (const float*)d_in[0];
    const int*   ei    = (const int*)  d_in[1];
    const float* eattr = (const float*)d_in[2];
    const int*   esrc  = (const int*)  d_in[3];
    const int*   etgt  = (const int*)  d_in[4];
    const float* W1l = (const float*)d_in[5];  const float* b1 = (const float*)d_in[6];
    const float* W1r = (const float*)d_in[7];
    const float* W2l = (const float*)d_in[8];  const float* b2 = (const float*)d_in[9];
    const float* W2r = (const float*)d_in[10];
    const float* bn1_g = (const float*)d_in[11]; const float* bn1_b = (const float*)d_in[12];
    const float* bn2_g = (const float*)d_in[13]; const float* bn2_b = (const float*)d_in[14];
    const float* We  = (const float*)d_in[15]; const float* be  = (const float*)d_in[16];
    const float* bne_g = (const float*)d_in[17]; const float* bne_b = (const float*)d_in[18];
    const float* Wm1 = (const float*)d_in[19]; const float* bm1 = (const float*)d_in[20];
    const float* bnm_g = (const float*)d_in[21]; const float* bnm_b = (const float*)d_in[22];
    const float* Wm2 = (const float*)d_in[23]; const float* bm2 = (const float*)d_in[24];
    const float* Wm3 = (const float*)d_in[25]; const float* bm3 = (const float*)d_in[26];
    float* out = (float*)d_out;

    char* base = (char*)d_ws;
    size_t o = 0;
    auto A = [&](size_t bytes) { char* p = base + o; o = (o + bytes + 255) & ~(size_t)255; return p; };
    short* hsb   = (short*)A((size_t)NN * 128 * 2);
    short* hdb   = (short*)A((size_t)NN * 128 * 2);
    short* ea_bf = (short*)A((size_t)NE * 16 * 2);
    int*   deg   = (int*)  A((size_t)NN * 4);
    int*   rowptr= (int*)  A((size_t)(NN + 1) * 4);
    int*   wp    = (int*)  A((size_t)NN * 4);
    int*   elist = (int*)  A((size_t)NE * 4);
    float* st    = (float*)A(1024 * 4);
    int*   bsum  = (int*)  A(SCAN_NB * 4);
    int*   boff  = (int*)  A(SCAN_NB * 4);
    float* bm1p  = (float*)A(512); float* b2p = (float*)A(256);
    short* WteT  = (short*)A(128 * 32 * 2);
    short* W1pT  = (short*)A(128 * 128 * 2);
    short* WmsT  = (short*)A(128 * 128 * 2);
    short* WmdT  = (short*)A(128 * 128 * 2);
    short* W2pT  = (short*)A(64 * 128 * 2);
    short* W2cT  = (short*)A(128 * 256 * 2);
    float* meanX = (float*)A((size_t)NN * 32 * 4);
    short* h1b   = (short*)A((size_t)NN * 128 * 2);
    short* m2b   = (short*)A((size_t)NN * 128 * 2);
    short* h2b   = (short*)A((size_t)NN * 128 * 2);
    int*   stmp  = (int*)meanX;   // scan tmp aliases meanX (dead until gagg1)

    hipMemsetAsync(deg, 0, (size_t)NN * 4, stream);
    hipMemsetAsync(st, 0, 1024 * 4, stream);

    // weight prep + CSR build
    k_prep<<<5, 128, 0, stream>>>(We, Wm1, W2l, W2r, WteT, WmsT, WmdT, W2cT);
    k_hist<<<(NE + 255) / 256, 256, 0, stream>>>(ei, deg);
    k_scan_a<<<SCAN_NB, 1024, 0, stream>>>(deg, stmp, bsum);
    k_scan_b<<<1, 64, 0, stream>>>(bsum, boff, rowptr);
    k_scan_c<<<SCAN_NB, 1024, 0, stream>>>(stmp, boff, rowptr, wp);
    k_scatter<<<(NE + 255) / 256, 256, 0, stream>>>(ei, wp, elist);

    // edge bne stats + ea->bf16
    k_edge_mfma<0><<<1024, 256, 0, stream>>>(eattr, ea_bf, WteT, be, W1pT, bm1p, hsb, hdb,
        esrc, etgt, W2pT, b2p, Wm3, bm3, st + 512, st + 640, out);
    k_fold_e<<<1, 128, 0, stream>>>(st + 512, st + 640, bne_g, bne_b, Wm1, bm1, W1pT, bm1p);

    // ---- layer 1 ----
    k_gagg1<<<NN / 8, 256, 0, stream>>>(x, rowptr, elist, meanX);
    k_node_l1<<<NN / 32, 256, 0, stream>>>(meanX, x, W1l, W1r, b1, h1b, st + 0, st + 128);

    // ---- layer 2 (bn1 finalized in-block) ----
    k_gagg2<<<NN / 8, 256, 0, stream>>>(h1b, rowptr, elist, st + 0, st + 128, bn1_g, bn1_b, m2b);
    k_node_l2m<<<640, 256, 0, stream>>>(m2b, h1b, st + 0, st + 128, bn1_g, bn1_b,
                                        W2cT, b2, h2b, st + 256, st + 384);

    // ---- node projections (bn2 finalized in-block) ----
    k_proj2<<<640, 256, 0, stream>>>(h2b, st + 256, st + 384, bn2_g, bn2_b, WmsT, WmdT, hsb, hdb);

    // ---- edge main (v + bnm stats) ----
    k_edge_mfma<1><<<2048, 256, 0, stream>>>(eattr, ea_bf, WteT, be, W1pT, bm1p, hsb, hdb,
        esrc, etgt, W2pT, b2p, Wm3, bm3, st + 768, st + 896, out);
    k_fold_m<<<1, 128, 0, stream>>>(st + 768, st + 896, bnm_g, bnm_b, Wm2, bm2, W2pT, b2p);

    // ---- edge final (recompute v; z2/out) ----
    k_edge_mfma<2><<<2048, 256, 0, stream>>>(eattr, ea_bf, WteT, be, W1pT, bm1p, hsb, hdb,
        esrc, etgt, W2pT, b2p, Wm3, bm3, nullptr, nullptr, out);
}